// Round 4
// baseline (22876.224 us; speedup 1.0000x reference)
//
#include <hip/hip_runtime.h>

typedef __attribute__((ext_vector_type(8))) short short8;
typedef __attribute__((ext_vector_type(4))) float floatx4;

#define TT 512
#define BB 64
#define HH 512
#define EE 300
#define NG 2048  // 4H

// ---- workspace layout (bytes) ----
// xfrag: [T][bt4][ch10][lane64][8] bf16          = 20,971,520 B
// Ufrag: [dir2][g4][jt32][hl2][ch16][64][8] bf16 =  8,388,608 B
// Wfrag: [dir2][g4][jt32][ch10][64][8] bf16      =  2,621,440 B
// hbuf : [par2][dir2][pl2][b64][k512] bf16       =    524,288 B
// ctr  : 128 ints (8 counters, 64B-spaced)       =        512 B
#define XF_ELEMS ((size_t)BB*TT*320)
#define UF_OFF   ((size_t)XF_ELEMS*2)
#define UF_ELEMS ((size_t)2*4*32*2*16*64*8)
#define WF_OFF   (UF_OFF + UF_ELEMS*2)
#define WF_ELEMS ((size_t)2*4*32*10*64*8)
#define HB_OFF   (WF_OFF + WF_ELEMS*2)
#define HB_SHORTS ((size_t)2*2*2*BB*HH)     // 262,144 shorts
#define CTR_OFF  (HB_OFF + HB_SHORTS*2)

__device__ __forceinline__ short f2bf(float f) {   // RNE
  union { float f; unsigned u; } v; v.f = f;
  unsigned r = v.u + 0x7fffu + ((v.u >> 16) & 1u);
  return (short)(r >> 16);
}
__device__ __forceinline__ float bf2f(short s) {
  union { unsigned u; float f; } v; v.u = ((unsigned)(unsigned short)s) << 16;
  return v.f;
}
__device__ __forceinline__ float fast_exp(float x) {
  return __builtin_amdgcn_exp2f(x * 1.44269504088896340736f);
}
__device__ __forceinline__ float sigm(float x) {   // NaN-free, saturates at +-inf
  return __builtin_amdgcn_rcpf(1.f + fast_exp(-x));
}
__device__ __forceinline__ float ftanh(float x) {  // 1 - 2/(e^2x+1), NaN-free
  return 1.f - 2.f * __builtin_amdgcn_rcpf(1.f + fast_exp(2.f * x));
}

// ---- prep: gather embeddings -> x A-fragments ----
__global__ void prep_x(const int* __restrict__ tokens, const float* __restrict__ emb,
                       short* __restrict__ xfrag) {
  int tid = blockIdx.x * 256 + threadIdx.x;      // B*T*64
  int q = tid & 63; int t = (tid >> 6) & 511; int b = tid >> 15;
  int ch = q >> 2, kg = q & 3;                   // ch 0..15; only 0..9 valid
  if (ch >= 10) return;
  int k0 = ch * 32 + kg * 8;
  int tok = tokens[b * TT + t];
  const float* er = emb + (size_t)tok * EE;
  short8 s;
#pragma unroll
  for (int i = 0; i < 8; ++i) {
    int k = k0 + i;
    float v = (k < EE) ? er[k] : 0.f;
    s[i] = f2bf(v);
  }
  int bt = b >> 4; int lane = kg * 16 + (b & 15);
  ((short8*)xfrag)[(((size_t)t * 4 + bt) * 10 + ch) * 64 + lane] = s;
}

// ---- prep: U (hi/lo) and W (single) -> B-fragments ----
__global__ void prep_uw(const float* __restrict__ U_fw, const float* __restrict__ U_bw,
                        const float* __restrict__ W_fw, const float* __restrict__ W_bw,
                        short* __restrict__ Ufrag, short* __restrict__ Wfrag) {
  int tid = blockIdx.x * 256 + threadIdx.x;      // 2*64*2048
  int n = tid & 2047; int k8 = (tid >> 11) & 63; int dir = tid >> 17;
  int g = n >> 9; int j = n & 511; int jt = j >> 4; int colr = j & 15;
  int ch = k8 >> 2; int kg = k8 & 3; int lane = kg * 16 + colr;
  const float* U = dir ? U_bw : U_fw;
  short8 hi, lo;
#pragma unroll
  for (int i = 0; i < 8; ++i) {
    float v = U[(size_t)(k8 * 8 + i) * NG + n];
    short h = f2bf(v); hi[i] = h;
    lo[i] = f2bf(v - bf2f(h));
  }
  short8* ub = (short8*)Ufrag;
  ub[((((size_t)(dir * 4 + g) * 32 + jt) * 2 + 0) * 16 + ch) * 64 + lane] = hi;
  ub[((((size_t)(dir * 4 + g) * 32 + jt) * 2 + 1) * 16 + ch) * 64 + lane] = lo;
  if (k8 < 40) {
    const float* W = dir ? W_bw : W_fw;
    short8 w;
#pragma unroll
    for (int i = 0; i < 8; ++i) {
      int k = k8 * 8 + i;
      float v = (k < EE) ? W[(size_t)k * NG + n] : 0.f;
      w[i] = f2bf(v);
    }
    ((short8*)Wfrag)[(((size_t)(dir * 4 + g) * 32 + jt) * 10 + ch) * 64 + lane] = w;
  }
}

// ---- prep: h0 -> hbuf parity-0 hi/lo planes, zero counters ----
__global__ void prep_h(const float* __restrict__ h0_fw, const float* __restrict__ h0_bw,
                       short* __restrict__ hbuf, int* __restrict__ ctr) {
  int tid = blockIdx.x * 256 + threadIdx.x;      // 65,536 = 2*32768
  if (tid < 128) ctr[tid] = 0;
  int dir = tid >> 15; int idx = tid & 32767;
  float v = (dir ? h0_bw : h0_fw)[idx];
  unsigned u = __builtin_bit_cast(unsigned, v);
  short hi = (short)(u >> 16);
  float hf = __builtin_bit_cast(float, u & 0xFFFF0000u);
  short lo = f2bf(v - hf);
  size_t base = (size_t)dir * 2 * 32768;         // parity 0
  hbuf[base + idx] = hi;
  hbuf[base + 32768 + idx] = lo;
}

// ---- persistent scan: 256 blocks x 512 threads (8 waves, K-split) ----
// blk = jt*8 + grp, grp = bt*2+dir  (group members share blk%8 -> same XCD)
__global__ void __launch_bounds__(512, 2)
lstm_scan(const short* __restrict__ xfrag, const short* __restrict__ Ufrag,
          const short* __restrict__ Wfrag, short* __restrict__ hbuf,
          int* __restrict__ ctr,
          const float* __restrict__ b_fw, const float* __restrict__ b_bw,
          const float* __restrict__ c0_fw, const float* __restrict__ c0_bw,
          float* __restrict__ out) {
  __shared__ float part[8 * 4 * 64 * 4];         // [w][g][lane][reg] f32, 32 KB
  const int blk = blockIdx.x, tid = threadIdx.x;
  const int grp = blk & 7, jt = blk >> 3;
  const int bt = grp >> 1, dir = grp & 1;
  const int w = tid >> 6, l = tid & 63;
  const int col = l & 15, kg = l >> 4;
  const short8 kz = {0, 0, 0, 0, 0, 0, 0, 0};
  const floatx4 fz = {0.f, 0.f, 0.f, 0.f};

  const short8* U8 = (const short8*)Ufrag;
  const short8* W8 = (const short8*)Wfrag;
  const short8* X8 = (const short8*)xfrag;

  // ---- persistent U (chunks 2w, 2w+1; hi+lo): 16 short8 = 64 VGPR ----
  short8 Uh[2][4], Ul[2][4];
#pragma unroll
  for (int cc = 0; cc < 2; ++cc) {
    int ch = 2 * w + cc;
#pragma unroll
    for (int g = 0; g < 4; ++g) {
      size_t base = (((size_t)(dir * 4 + g) * 32 + jt) * 2 * 16 + ch) * 64 + l;
      Uh[cc][g] = U8[base];
      Ul[cc][g] = U8[base + (size_t)16 * 64];
    }
  }
  // ---- persistent W for this wave's x-chunks ----
  const int xc0 = w;
  const int xc1 = (w < 2) ? (8 + w) : -1;
  short8 Wr0[4], Wr1[4];
#pragma unroll
  for (int g = 0; g < 4; ++g) {
    Wr0[g] = W8[(((size_t)(dir * 4 + g) * 32 + jt) * 10 + xc0) * 64 + l];
    Wr1[g] = (xc1 >= 0) ? W8[(((size_t)(dir * 4 + g) * 32 + jt) * 10 + xc1) * 64 + l] : kz;
  }

  // ---- pointwise ownership (tid<256): one (b_loc, jj) pair ----
  const int b_loc = (tid >> 4) & 15, jj = tid & 15;
  const int lane_src = ((tid >> 6) << 4) | jj;   // C/D: lane=(b&15)/4*16+j... (b_loc>>2)*16+jj
  const int reg_src = (tid >> 4) & 3;            //      reg=b_loc&3
  float bg[4] = {0.f, 0.f, 0.f, 0.f};
  float cst = 0.f;
  if (tid < 256) {
    const float* bias = dir ? b_bw : b_fw;
#pragma unroll
    for (int g = 0; g < 4; ++g) bg[g] = bias[g * 512 + jt * 16 + jj];
    const float* c0 = dir ? c0_bw : c0_fw;
    cst = c0[(size_t)(bt * 16 + b_loc) * HH + jt * 16 + jj];
  }

  // ---- x prefetch for t=0 ----
  const int te0 = dir ? (TT - 1) : 0;
  short8 xa0 = X8[(((size_t)te0 * 4 + bt) * 10 + xc0) * 64 + l];
  short8 xa1 = (xc1 >= 0) ? X8[(((size_t)te0 * 4 + bt) * 10 + xc1) * 64 + l] : kz;

  int* myctr = ctr + grp * 16;

  for (int t = 0; t < TT; ++t) {
    // ---- 1. x-part MFMAs (independent of h(t)) BEFORE the barrier wait ----
    floatx4 acc[4];
#pragma unroll
    for (int g = 0; g < 4; ++g) acc[g] = fz;
#pragma unroll
    for (int g = 0; g < 4; ++g)
      acc[g] = __builtin_amdgcn_mfma_f32_16x16x32_bf16(xa0, Wr0[g], acc[g], 0, 0, 0);
    if (xc1 >= 0) {
#pragma unroll
      for (int g = 0; g < 4; ++g)
        acc[g] = __builtin_amdgcn_mfma_f32_16x16x32_bf16(xa1, Wr1[g], acc[g], 0, 0, 0);
    }

    // ---- 2. wait for h(t) from the 31 sibling blocks ----
    if (t > 0) {
      if (tid == 0) {
        const int target = 32 * t;
        while (__hip_atomic_load(myctr, __ATOMIC_ACQUIRE, __HIP_MEMORY_SCOPE_AGENT) < target)
          __builtin_amdgcn_s_sleep(2);
      }
      __syncthreads();
    }

    // ---- 3. load h(t) hi/lo bf16 fragments (no split VALU needed) ----
    const short* hb = hbuf + ((size_t)(t & 1) * 2 + dir) * 2 * 32768;
    const size_t ho = (size_t)(bt * 16 + col) * 512 + kg * 8;
    short8 ahi[2], alo[2];
#pragma unroll
    for (int cc = 0; cc < 2; ++cc) {
      ahi[cc] = *(const short8*)(hb + ho + (2 * w + cc) * 32);
      alo[cc] = *(const short8*)(hb + 32768 + ho + (2 * w + cc) * 32);
    }

    // ---- 4. recurrent MFMAs: hi*Uhi + lo*Uhi + hi*Ulo ----
#pragma unroll
    for (int cc = 0; cc < 2; ++cc) {
#pragma unroll
      for (int g = 0; g < 4; ++g)
        acc[g] = __builtin_amdgcn_mfma_f32_16x16x32_bf16(ahi[cc], Uh[cc][g], acc[g], 0, 0, 0);
#pragma unroll
      for (int g = 0; g < 4; ++g)
        acc[g] = __builtin_amdgcn_mfma_f32_16x16x32_bf16(alo[cc], Uh[cc][g], acc[g], 0, 0, 0);
#pragma unroll
      for (int g = 0; g < 4; ++g)
        acc[g] = __builtin_amdgcn_mfma_f32_16x16x32_bf16(ahi[cc], Ul[cc][g], acc[g], 0, 0, 0);
    }

    // ---- 5. prefetch x(t+1) (hides under MFMA/reduce) ----
    short8 xn0 = kz, xn1 = kz;
    if (t + 1 < TT) {
      int te = dir ? (TT - 2 - t) : (t + 1);
      xn0 = X8[(((size_t)te * 4 + bt) * 10 + xc0) * 64 + l];
      if (xc1 >= 0) xn1 = X8[(((size_t)te * 4 + bt) * 10 + xc1) * 64 + l];
    }

    // ---- 6. reduce partials through LDS; pointwise update ----
#pragma unroll
    for (int g = 0; g < 4; ++g)
      *(floatx4*)&part[(((size_t)w * 4 + g) * 64 + l) * 4] = acc[g];
    __syncthreads();

    if (tid < 256) {
      float z[4];
#pragma unroll
      for (int g = 0; g < 4; ++g) {
        float s = bg[g];
#pragma unroll
        for (int ww = 0; ww < 8; ++ww)
          s += part[((ww * 4 + g) * 64 + lane_src) * 4 + reg_src];
        z[g] = s;
      }
      float ig = sigm(z[0]), fg = sigm(z[1]), gv = ftanh(z[2]), og = sigm(z[3]);
      float cn = fg * cst + ig * gv;
      cst = cn;
      float h = og * ftanh(cn);
      // split h -> bf16 hi/lo planes for parity (t+1)
      unsigned hu = __builtin_bit_cast(unsigned, h);
      short hhi = (short)(hu >> 16);
      float hhf = __builtin_bit_cast(float, hu & 0xFFFF0000u);
      short hlo = f2bf(h - hhf);
      short* hn = hbuf + ((size_t)((t + 1) & 1) * 2 + dir) * 2 * 32768;
      int bglob = bt * 16 + b_loc;
      int jcol = jt * 16 + jj;
      hn[(size_t)bglob * 512 + jcol] = hhi;
      hn[32768 + (size_t)bglob * 512 + jcol] = hlo;
      int te = dir ? (TT - 1 - t) : t;
      out[((size_t)bglob * TT + te) * 1024 + dir * 512 + jcol] = h;
      if (t == TT - 1) {
        out[(size_t)BB * TT * 1024 + (size_t)bglob * 1024 + dir * 512 + jcol] = h;
        out[(size_t)BB * TT * 1024 + (size_t)BB * 1024 + (size_t)bglob * 1024 + dir * 512 + jcol] = cn;
      }
    }

    // ---- 7. publish h(t+1) ----
    if (t + 1 < TT) {
      __threadfence();
      __syncthreads();
      if (tid == 0)
        __hip_atomic_fetch_add(myctr, 1, __ATOMIC_RELEASE, __HIP_MEMORY_SCOPE_AGENT);
    }
    xa0 = xn0;
    xa1 = xn1;
  }
}

extern "C" void kernel_launch(void* const* d_in, const int* in_sizes, int n_in,
                              void* d_out, int out_size, void* d_ws, size_t ws_size,
                              hipStream_t stream) {
  const int*   tokens = (const int*)d_in[0];
  const float* h0_fw  = (const float*)d_in[1];
  const float* c0_fw  = (const float*)d_in[2];
  const float* h0_bw  = (const float*)d_in[3];
  const float* c0_bw  = (const float*)d_in[4];
  const float* emb    = (const float*)d_in[5];
  const float* W_fw   = (const float*)d_in[6];
  const float* U_fw   = (const float*)d_in[7];
  const float* b_fw   = (const float*)d_in[8];
  const float* W_bw   = (const float*)d_in[9];
  const float* U_bw   = (const float*)d_in[10];
  const float* b_bw   = (const float*)d_in[11];
  float* out = (float*)d_out;

  char* ws = (char*)d_ws;
  short* xfrag = (short*)(ws);
  short* Ufrag = (short*)(ws + UF_OFF);
  short* Wfrag = (short*)(ws + WF_OFF);
  short* hbuf  = (short*)(ws + HB_OFF);
  int*   ctr   = (int*)(ws + CTR_OFF);

  prep_x<<<8192, 256, 0, stream>>>(tokens, emb, xfrag);
  prep_uw<<<1024, 256, 0, stream>>>(U_fw, U_bw, W_fw, W_bw, Ufrag, Wfrag);
  prep_h<<<256, 256, 0, stream>>>(h0_fw, h0_bw, hbuf, ctr);

  void* args[] = {(void*)&xfrag, (void*)&Ufrag, (void*)&Wfrag, (void*)&hbuf,
                  (void*)&ctr, (void*)&b_fw, (void*)&b_bw, (void*)&c0_fw,
                  (void*)&c0_bw, (void*)&out};
  hipLaunchCooperativeKernel((void*)lstm_scan, dim3(256), dim3(512), args, 0, stream);
}

// Round 7
// 2175.974 us; speedup vs baseline: 10.5131x; 10.5131x over previous
//
#include <hip/hip_runtime.h>

typedef __attribute__((ext_vector_type(8))) short short8;
typedef __attribute__((ext_vector_type(4))) float floatx4;

#define TT 512
#define BB 64
#define HH 512
#define EE 300
#define NG 2048  // 4H

// ---- workspace layout (bytes) ----
// xfrag: [T][bt4][ch10][lane64][8] bf16          = 20,971,520 B
// Ufrag: [dir2][g4][jt32][hl2][ch16][64][8] bf16 =  8,388,608 B
// Wfrag: [dir2][g4][jt32][ch10][64][8] bf16      =  2,621,440 B
// hpk  : [par2][dir2][b64][j512] u32 (hi|lo<<16) =    524,288 B
// flags: 8 groups x 64 ints                      =      2,048 B
#define XF_ELEMS ((size_t)BB*TT*320)
#define UF_OFF   ((size_t)XF_ELEMS*2)
#define UF_ELEMS ((size_t)2*4*32*2*16*64*8)
#define WF_OFF   (UF_OFF + UF_ELEMS*2)
#define WF_ELEMS ((size_t)2*4*32*10*64*8)
#define HP_OFF   (WF_OFF + WF_ELEMS*2)
#define HP_WORDS ((size_t)2*2*BB*HH)        // 131,072 u32
#define FL_OFF   (HP_OFF + HP_WORDS*4)

__device__ __forceinline__ short f2bf(float f) {   // RNE
  union { float f; unsigned u; } v; v.f = f;
  unsigned r = v.u + 0x7fffu + ((v.u >> 16) & 1u);
  return (short)(r >> 16);
}
__device__ __forceinline__ float bf2f(short s) {
  union { unsigned u; float f; } v; v.u = ((unsigned)(unsigned short)s) << 16;
  return v.f;
}
__device__ __forceinline__ float fast_exp(float x) {
  return __builtin_amdgcn_exp2f(x * 1.44269504088896340736f);
}
__device__ __forceinline__ float sigm(float x) {   // NaN-free, saturates at +-inf
  return __builtin_amdgcn_rcpf(1.f + fast_exp(-x));
}
__device__ __forceinline__ float ftanh(float x) {  // 1 - 2/(e^2x+1), NaN-free
  return 1.f - 2.f * __builtin_amdgcn_rcpf(1.f + fast_exp(2.f * x));
}

// ---- prep: gather embeddings -> x A-fragments ----
__global__ void prep_x(const int* __restrict__ tokens, const float* __restrict__ emb,
                       short* __restrict__ xfrag) {
  int tid = blockIdx.x * 256 + threadIdx.x;      // B*T*64
  int q = tid & 63; int t = (tid >> 6) & 511; int b = tid >> 15;
  int ch = q >> 2, kg = q & 3;                   // ch 0..15; only 0..9 valid
  if (ch >= 10) return;
  int k0 = ch * 32 + kg * 8;
  int tok = tokens[b * TT + t];
  const float* er = emb + (size_t)tok * EE;
  short8 s;
#pragma unroll
  for (int i = 0; i < 8; ++i) {
    int k = k0 + i;
    float v = (k < EE) ? er[k] : 0.f;
    s[i] = f2bf(v);
  }
  int bt = b >> 4; int lane = kg * 16 + (b & 15);
  ((short8*)xfrag)[(((size_t)t * 4 + bt) * 10 + ch) * 64 + lane] = s;
}

// ---- prep: U (hi/lo) and W (single) -> B-fragments ----
__global__ void prep_uw(const float* __restrict__ U_fw, const float* __restrict__ U_bw,
                        const float* __restrict__ W_fw, const float* __restrict__ W_bw,
                        short* __restrict__ Ufrag, short* __restrict__ Wfrag) {
  int tid = blockIdx.x * 256 + threadIdx.x;      // 2*64*2048
  int n = tid & 2047; int k8 = (tid >> 11) & 63; int dir = tid >> 17;
  int g = n >> 9; int j = n & 511; int jt = j >> 4; int colr = j & 15;
  int ch = k8 >> 2; int kg = k8 & 3; int lane = kg * 16 + colr;
  const float* U = dir ? U_bw : U_fw;
  short8 hi, lo;
#pragma unroll
  for (int i = 0; i < 8; ++i) {
    float v = U[(size_t)(k8 * 8 + i) * NG + n];
    short h = f2bf(v); hi[i] = h;
    lo[i] = f2bf(v - bf2f(h));
  }
  short8* ub = (short8*)Ufrag;
  ub[((((size_t)(dir * 4 + g) * 32 + jt) * 2 + 0) * 16 + ch) * 64 + lane] = hi;
  ub[((((size_t)(dir * 4 + g) * 32 + jt) * 2 + 1) * 16 + ch) * 64 + lane] = lo;
  if (k8 < 40) {
    const float* W = dir ? W_bw : W_fw;
    short8 w;
#pragma unroll
    for (int i = 0; i < 8; ++i) {
      int k = k8 * 8 + i;
      float v = (k < EE) ? W[(size_t)k * NG + n] : 0.f;
      w[i] = f2bf(v);
    }
    ((short8*)Wfrag)[(((size_t)(dir * 4 + g) * 32 + jt) * 10 + ch) * 64 + lane] = w;
  }
}

// ---- prep: h0 -> hpk parity-0 (packed hi|lo<<16), zero flags ----
__global__ void prep_h(const float* __restrict__ h0_fw, const float* __restrict__ h0_bw,
                       unsigned* __restrict__ hpk, int* __restrict__ flags) {
  int tid = blockIdx.x * 256 + threadIdx.x;      // 65,536 = 2*32768
  if (tid < 512) flags[tid] = 0;
  int dir = tid >> 15; int idx = tid & 32767;
  float v = (dir ? h0_bw : h0_fw)[idx];
  unsigned u = __builtin_bit_cast(unsigned, v);
  unsigned short hi = (unsigned short)(u >> 16);
  float hf = __builtin_bit_cast(float, u & 0xFFFF0000u);
  unsigned short lo = (unsigned short)f2bf(v - hf);
  hpk[(size_t)dir * 32768 + idx] = (unsigned)hi | ((unsigned)lo << 16);  // parity 0
}

// ---- persistent scan: 256 blocks x 512 threads (8 waves, K-split) ----
// blk = jt*8 + grp, grp = bt*2+dir
// Sync protocol (fence-free): h exchanged via relaxed AGENT atomics (sc0/sc1,
// MALL-coherent). Producer: h stores -> s_waitcnt vmcnt(0) -> __syncthreads
// (all waves' store-acks drained) -> one relaxed flag store per block.
// Consumer: wave 0 polls 32 sibling flags, BOUNDED at 2^14 iters (hang-proof:
// broken protocol => fast validation failure, not a wedged GPU/watchdog kill).
__global__ void __launch_bounds__(512, 1)
lstm_scan(const short* __restrict__ xfrag, const short* __restrict__ Ufrag,
          const short* __restrict__ Wfrag, unsigned* __restrict__ hpk,
          int* __restrict__ flags,
          const float* __restrict__ b_fw, const float* __restrict__ b_bw,
          const float* __restrict__ c0_fw, const float* __restrict__ c0_bw,
          float* __restrict__ out) {
  __shared__ float part[8 * 4 * 64 * 4];         // [w][g][lane][reg] f32, 32 KB
  const int blk = blockIdx.x, tid = threadIdx.x;
  const int grp = blk & 7, jt = blk >> 3;
  const int bt = grp >> 1, dir = grp & 1;
  const int w = tid >> 6, l = tid & 63;
  const int col = l & 15, kg = l >> 4;
  const short8 kz = {0, 0, 0, 0, 0, 0, 0, 0};
  const floatx4 fz = {0.f, 0.f, 0.f, 0.f};

  const short8* U8 = (const short8*)Ufrag;
  const short8* W8 = (const short8*)Wfrag;
  const short8* X8 = (const short8*)xfrag;

  // ---- persistent U (chunks 2w, 2w+1; hi+lo): 16 short8 = 64 VGPR ----
  short8 Uh[2][4], Ul[2][4];
#pragma unroll
  for (int cc = 0; cc < 2; ++cc) {
    int ch = 2 * w + cc;
#pragma unroll
    for (int g = 0; g < 4; ++g) {
      size_t base = (((size_t)(dir * 4 + g) * 32 + jt) * 2 * 16 + ch) * 64 + l;
      Uh[cc][g] = U8[base];
      Ul[cc][g] = U8[base + (size_t)16 * 64];
    }
  }
  // ---- persistent W for this wave's x-chunks ----
  const int xc0 = w;
  const int xc1 = (w < 2) ? (8 + w) : -1;
  short8 Wr0[4], Wr1[4];
#pragma unroll
  for (int g = 0; g < 4; ++g) {
    Wr0[g] = W8[(((size_t)(dir * 4 + g) * 32 + jt) * 10 + xc0) * 64 + l];
    Wr1[g] = (xc1 >= 0) ? W8[(((size_t)(dir * 4 + g) * 32 + jt) * 10 + xc1) * 64 + l] : kz;
  }

  // ---- pointwise ownership (tid<256): one (b_loc, jj) pair ----
  const int b_loc = (tid >> 4) & 15, jj = tid & 15;
  const int lane_src = ((tid >> 6) << 4) | jj;   // C/D: lane=(b_loc>>2)*16+jj
  const int reg_src = (tid >> 4) & 3;            //      reg=b_loc&3
  float bg[4] = {0.f, 0.f, 0.f, 0.f};
  float cst = 0.f;
  if (tid < 256) {
    const float* bias = dir ? b_bw : b_fw;
#pragma unroll
    for (int g = 0; g < 4; ++g) bg[g] = bias[g * 512 + jt * 16 + jj];
    const float* c0 = dir ? c0_bw : c0_fw;
    cst = c0[(size_t)(bt * 16 + b_loc) * HH + jt * 16 + jj];
  }

  // ---- x prefetch for t=0 ----
  const int te0 = dir ? (TT - 1) : 0;
  short8 xa0 = X8[(((size_t)te0 * 4 + bt) * 10 + xc0) * 64 + l];
  short8 xa1 = (xc1 >= 0) ? X8[(((size_t)te0 * 4 + bt) * 10 + xc1) * 64 + l] : kz;

  int* myflags = flags + grp * 64;

  for (int t = 0; t < TT; ++t) {
    // ---- 1. x-part MFMAs (independent of h(t)) BEFORE the flag wait ----
    floatx4 acc[4];
#pragma unroll
    for (int g = 0; g < 4; ++g) acc[g] = fz;
#pragma unroll
    for (int g = 0; g < 4; ++g)
      acc[g] = __builtin_amdgcn_mfma_f32_16x16x32_bf16(xa0, Wr0[g], acc[g], 0, 0, 0);
    if (xc1 >= 0) {
#pragma unroll
      for (int g = 0; g < 4; ++g)
        acc[g] = __builtin_amdgcn_mfma_f32_16x16x32_bf16(xa1, Wr1[g], acc[g], 0, 0, 0);
    }

    // ---- 2. wait for the 32 sibling flags (wave 0 polls, bounded) ----
    if (t > 0) {
      if (w == 0) {
        for (int spin = 0; spin < (1 << 14); ++spin) {
          int f = __hip_atomic_load(&myflags[l & 31], __ATOMIC_RELAXED,
                                    __HIP_MEMORY_SCOPE_AGENT);
          if (__all(f >= t)) break;
          __builtin_amdgcn_s_sleep(1);
        }
      }
      __syncthreads();
    }

    // ---- 3. load h(t) packed u32 via coherent (sc0/sc1) 8B atomic loads ----
    const unsigned* hp = hpk + ((size_t)(t & 1) * 2 + dir) * (BB * HH);
    const size_t ho = (size_t)(bt * 16 + col) * HH;
    short8 ahi[2], alo[2];
#pragma unroll
    for (int cc = 0; cc < 2; ++cc) {
      int k0 = (2 * w + cc) * 32 + kg * 8;
      const unsigned long long* p = (const unsigned long long*)(hp + ho + k0);
#pragma unroll
      for (int q = 0; q < 4; ++q) {
        unsigned long long u = __hip_atomic_load(&p[q], __ATOMIC_RELAXED,
                                                 __HIP_MEMORY_SCOPE_AGENT);
        unsigned u0 = (unsigned)u, u1 = (unsigned)(u >> 32);
        ahi[cc][2 * q]     = (short)(u0 & 0xffffu);
        alo[cc][2 * q]     = (short)(u0 >> 16);
        ahi[cc][2 * q + 1] = (short)(u1 & 0xffffu);
        alo[cc][2 * q + 1] = (short)(u1 >> 16);
      }
    }

    // ---- 4. recurrent MFMAs: hi*Uhi + lo*Uhi + hi*Ulo ----
#pragma unroll
    for (int cc = 0; cc < 2; ++cc) {
#pragma unroll
      for (int g = 0; g < 4; ++g)
        acc[g] = __builtin_amdgcn_mfma_f32_16x16x32_bf16(ahi[cc], Uh[cc][g], acc[g], 0, 0, 0);
#pragma unroll
      for (int g = 0; g < 4; ++g)
        acc[g] = __builtin_amdgcn_mfma_f32_16x16x32_bf16(alo[cc], Uh[cc][g], acc[g], 0, 0, 0);
#pragma unroll
      for (int g = 0; g < 4; ++g)
        acc[g] = __builtin_amdgcn_mfma_f32_16x16x32_bf16(ahi[cc], Ul[cc][g], acc[g], 0, 0, 0);
    }

    // ---- 5. prefetch x(t+1) ----
    short8 xn0 = kz, xn1 = kz;
    if (t + 1 < TT) {
      int te = dir ? (TT - 2 - t) : (t + 1);
      xn0 = X8[(((size_t)te * 4 + bt) * 10 + xc0) * 64 + l];
      if (xc1 >= 0) xn1 = X8[(((size_t)te * 4 + bt) * 10 + xc1) * 64 + l];
    }

    // ---- 6. reduce partials through LDS; pointwise update ----
#pragma unroll
    for (int g = 0; g < 4; ++g)
      *(floatx4*)&part[(((size_t)w * 4 + g) * 64 + l) * 4] = acc[g];
    __syncthreads();

    if (tid < 256) {
      float z[4];
#pragma unroll
      for (int g = 0; g < 4; ++g) {
        float s = bg[g];
#pragma unroll
        for (int ww = 0; ww < 8; ++ww)
          s += part[((ww * 4 + g) * 64 + lane_src) * 4 + reg_src];
        z[g] = s;
      }
      float ig = sigm(z[0]), fg = sigm(z[1]), gv = ftanh(z[2]), og = sigm(z[3]);
      float cn = fg * cst + ig * gv;
      cst = cn;
      float h = og * ftanh(cn);
      // pack h -> u32 (hi | lo<<16), store coherent for parity (t+1)
      unsigned hu = __builtin_bit_cast(unsigned, h);
      unsigned short hhi = (unsigned short)(hu >> 16);
      float hhf = __builtin_bit_cast(float, hu & 0xFFFF0000u);
      unsigned short hlo = (unsigned short)f2bf(h - hhf);
      unsigned packed = (unsigned)hhi | ((unsigned)hlo << 16);
      unsigned* hn = hpk + ((size_t)((t + 1) & 1) * 2 + dir) * (BB * HH);
      int bglob = bt * 16 + b_loc;
      int jcol = jt * 16 + jj;
      __hip_atomic_store(&hn[(size_t)bglob * HH + jcol], packed, __ATOMIC_RELAXED,
                         __HIP_MEMORY_SCOPE_AGENT);
      int te = dir ? (TT - 1 - t) : t;
      out[((size_t)bglob * TT + te) * 1024 + dir * 512 + jcol] = h;
      if (t == TT - 1) {
        out[(size_t)BB * TT * 1024 + (size_t)bglob * 1024 + dir * 512 + jcol] = h;
        out[(size_t)BB * TT * 1024 + (size_t)BB * 1024 + (size_t)bglob * 1024 + dir * 512 + jcol] = cn;
      }
    }

    // ---- 7. publish: drain store-acks block-wide, then one flag store ----
    if (t + 1 < TT) {
      asm volatile("s_waitcnt vmcnt(0)" ::: "memory");
      __syncthreads();
      if (tid == 0)
        __hip_atomic_store(&myflags[jt], t + 1, __ATOMIC_RELAXED,
                           __HIP_MEMORY_SCOPE_AGENT);
    }
    xa0 = xn0;
    xa1 = xn1;
  }
}

extern "C" void kernel_launch(void* const* d_in, const int* in_sizes, int n_in,
                              void* d_out, int out_size, void* d_ws, size_t ws_size,
                              hipStream_t stream) {
  const int*   tokens = (const int*)d_in[0];
  const float* h0_fw  = (const float*)d_in[1];
  const float* c0_fw  = (const float*)d_in[2];
  const float* h0_bw  = (const float*)d_in[3];
  const float* c0_bw  = (const float*)d_in[4];
  const float* emb    = (const float*)d_in[5];
  const float* W_fw   = (const float*)d_in[6];
  const float* U_fw   = (const float*)d_in[7];
  const float* b_fw   = (const float*)d_in[8];
  const float* W_bw   = (const float*)d_in[9];
  const float* U_bw   = (const float*)d_in[10];
  const float* b_bw   = (const float*)d_in[11];
  float* out = (float*)d_out;

  char* ws = (char*)d_ws;
  short*    xfrag = (short*)(ws);
  short*    Ufrag = (short*)(ws + UF_OFF);
  short*    Wfrag = (short*)(ws + WF_OFF);
  unsigned* hpk   = (unsigned*)(ws + HP_OFF);
  int*      flags = (int*)(ws + FL_OFF);

  prep_x<<<8192, 256, 0, stream>>>(tokens, emb, xfrag);
  prep_uw<<<1024, 256, 0, stream>>>(U_fw, U_bw, W_fw, W_bw, Ufrag, Wfrag);
  prep_h<<<256, 256, 0, stream>>>(h0_fw, h0_bw, hpk, flags);

  void* args[] = {(void*)&xfrag, (void*)&Ufrag, (void*)&Wfrag, (void*)&hpk,
                  (void*)&flags, (void*)&b_fw, (void*)&b_bw, (void*)&c0_fw,
                  (void*)&c0_bw, (void*)&out};
  hipLaunchCooperativeKernel((void*)lstm_scan, dim3(256), dim3(512), args, 0, stream);
}